// Round 14
// baseline (395.664 us; speedup 1.0000x reference)
//
#include <hip/hip_runtime.h>

typedef __attribute__((ext_vector_type(8))) short bf16x8;
typedef __attribute__((ext_vector_type(4))) float f32x4;
typedef __attribute__((ext_vector_type(2))) float f32x2;

// bf16 round-to-nearest-even
__device__ inline unsigned short bf16_rtn(float f) {
  unsigned u = __float_as_uint(f);
  unsigned r = u + 0x7fffu + ((u >> 16) & 1u);
  return (unsigned short)(r >> 16);
}

// split fp32 into hi/lo bf16 (for W only)
__device__ inline void split_bf16(float f, unsigned short& hi, unsigned short& lo) {
  hi = bf16_rtn(f);
  float fh = __uint_as_float((unsigned)hi << 16);
  lo = bf16_rtn(f - fh);
}

__device__ inline float bf16_to_f(unsigned short v) {
  return __uint_as_float((unsigned)v << 16);
}

// fp8 e4m3 (OCP) pack/unpack via HW converters
__device__ inline unsigned char f_to_fp8(float f) {
  int r = __builtin_amdgcn_cvt_pk_fp8_f32(f, f, 0, false);
  return (unsigned char)(r & 0xff);
}
__device__ inline f32x2 fp8x2_to_f(unsigned short v) {
  return __builtin_amdgcn_cvt_pk_f32_fp8((int)v, false);
}

// ---------------- init: zero deg + gstart/gend/pooled, prep W hi/lo, T ----------------
__global__ void k_init(int* __restrict__ deg, int* __restrict__ gpz, int N, int M,
                       const float* __restrict__ Ws, const float* __restrict__ embed,
                       unsigned short* __restrict__ wphi,
                       unsigned short* __restrict__ wplo,
                       float* __restrict__ T) {
  int i = blockIdx.x * 256 + threadIdx.x;
  if (i < N) deg[i] = 0;
  if (i < M) gpz[i] = 0;
  int l = blockIdx.x;
  if (l < 3) {
    const float* W = Ws + (size_t)(l + 1) * 128 * 128;
    unsigned short* dh = wphi + (size_t)l * 16384;
    unsigned short* dl = wplo + (size_t)l * 16384;
    for (int idx = threadIdx.x; idx < 16384; idx += 256) {
      int j = idx & 7;
      int lane = (idx >> 3) & 63;
      int c = (idx >> 9) & 3;
      int ct = idx >> 11;
      int k = c * 32 + ((lane >> 4) * 8) + j;
      int n = ct * 16 + (lane & 15);
      unsigned short hi, lo;
      split_bf16(W[k * 128 + n], hi, lo);
      dh[idx] = hi;
      dl[idx] = lo;
    }
  } else if (l == 3) {
    int t = threadIdx.x;
    int r = t >> 7, c = t & 127;
    float acc = 0.f;
    for (int k = 0; k < 128; ++k)
      acc += embed[r * 128 + k] * Ws[k * 128 + c];
    T[r * 128 + c] = acc;
  }
}

// ---------------- CSR construction ----------------

__global__ void k_hist(const int* __restrict__ dst, int* __restrict__ deg,
                       int* __restrict__ posr, int E) {
  int e = blockIdx.x * 256 + threadIdx.x;
  if (e < E) posr[e] = atomicAdd(&deg[dst[e]], 1);
}

__global__ void k_scan1(const int* __restrict__ deg, int* __restrict__ rowptr,
                        int* __restrict__ bsum, float* __restrict__ dpk,
                        const int* __restrict__ x, const int* __restrict__ batch,
                        int* __restrict__ gstart, int* __restrict__ gend, int N) {
  __shared__ int s[256];
  int t = threadIdx.x;
  int i = blockIdx.x * 256 + t;
  int v = (i < N) ? deg[i] : 0;
  if (i < N) {
    float di = rsqrtf((float)v + 1.0f);
    dpk[i] = x[i] ? -di : di;
    int g = batch[i];
    if (i == 0 || batch[i - 1] != g) gstart[g] = i;
    if (i == N - 1 || batch[i + 1] != g) gend[g] = i + 1;
  }
  s[t] = v;
  __syncthreads();
  for (int off = 1; off < 256; off <<= 1) {
    int u = (t >= off) ? s[t - off] : 0;
    __syncthreads();
    s[t] += u;
    __syncthreads();
  }
  if (i < N) rowptr[i] = s[t] - v;
  if (t == 255) bsum[blockIdx.x] = s[255];
}

__global__ void k_scan2(const int* __restrict__ bsum, int* __restrict__ boff, int nb) {
  __shared__ int s[512];
  int t = threadIdx.x;
  int v = (t < nb) ? bsum[t] : 0;
  s[t] = v;
  __syncthreads();
  for (int off = 1; off < 512; off <<= 1) {
    int u = (t >= off) ? s[t - off] : 0;
    __syncthreads();
    s[t] += u;
    __syncthreads();
  }
  boff[t] = s[t] - v;
}

__global__ void k_scan3(int* __restrict__ rowptr, const int* __restrict__ boff,
                        int N, int E) {
  int i = blockIdx.x * 256 + threadIdx.x;
  if (i < N) rowptr[i] += boff[i >> 8];
  if (i == 0) rowptr[N] = E;
}

__global__ void k_scatter(const int* __restrict__ src, const int* __restrict__ dst,
                          const int* __restrict__ posr, const int* __restrict__ rowptr,
                          const float* __restrict__ dpk,
                          int2* __restrict__ epack, int E) {
  int e = blockIdx.x * 256 + threadIdx.x;
  if (e >= E) return;
  int s = src[e], d = dst[e];
  int pos = rowptr[d] + posr[e];
  epack[pos] = make_int2(s, __float_as_int(dpk[s]));
}

// ---------------- per-node gather: predicated batch-8 (max MLP per node) ----------------
__device__ inline void gather_node(const unsigned char* __restrict__ tin,
                                   const int2* __restrict__ epack,
                                   int r0, int deg, int lane,
                                   float& a0, float& a1) {
  int dcap = deg < 64 ? deg : 64;
  int sl = 0;
  if (lane < dcap) sl = epack[r0 + lane].x;
  a0 = 0.f; a1 = 0.f;
  for (int e = 0; e < dcap; e += 8) {
    int cnt = dcap - e;               // wave-uniform
    if (cnt > 8) cnt = 8;
    unsigned short pp[8];
    #pragma unroll
    for (int u = 0; u < 8; ++u) {
      if (u < cnt) {                  // wave-uniform guard; loads independent
        int s = __shfl(sl, e + u, 64);
        pp[u] = *(const unsigned short*)(tin + (size_t)s * 128 + 2 * lane);
      }
    }
    #pragma unroll
    for (int u = 0; u < 8; ++u) {
      if (u < cnt) {
        f32x2 v = fp8x2_to_f(pp[u]);
        a0 += v.x;
        a1 += v.y;
      }
    }
  }
  for (int ee = r0 + 64; ee < r0 + deg; ++ee) {   // rare: deg > 64
    int s = epack[ee].x;
    unsigned short p = *(const unsigned short*)(tin + (size_t)s * 128 + 2 * lane);
    f32x2 v = fp8x2_to_f(p);
    a0 += v.x;
    a1 += v.y;
  }
}

// ---------------- standalone aggregate: h = relu(dinv_i*(sum t' + t'_i) + b) ----------------
__global__ void k_agg(const unsigned char* __restrict__ tin,
                      const int* __restrict__ rowptr,
                      const int2* __restrict__ epack,
                      const float* __restrict__ dpk, const float* __restrict__ bvec,
                      unsigned short* __restrict__ h, int N) {
  int i = (blockIdx.x * blockDim.x + threadIdx.x) >> 6;
  int lane = threadIdx.x & 63;
  if (i >= N) return;
  int r0 = rowptr[i], r1 = rowptr[i + 1];
  // prefetch independents before the gather
  unsigned short ps = *(const unsigned short*)(tin + (size_t)i * 128 + 2 * lane);
  float dp = dpk[i];
  float2 bv = *(const float2*)(bvec + 2 * lane);
  float a0, a1;
  gather_node(tin, epack, r0, r1 - r0, lane, a0, a1);
  f32x2 sv = fp8x2_to_f(ps);
  float di = fabsf(dp);
  a0 = fmaxf(di * (a0 + sv.x) + bv.x, 0.f);
  a1 = fmaxf(di * (a1 + sv.y) + bv.y, 0.f);
  *(unsigned*)(h + (size_t)i * 128 + 2 * lane) =
      (unsigned)bf16_rtn(a0) | ((unsigned)bf16_rtn(a1) << 16);
}

// ---------------- fused final aggregate + mean-pool (block = 4 nodes) ----------------
__global__ void k_agg_pool(const unsigned char* __restrict__ tin,
                           const int* __restrict__ rowptr,
                           const int2* __restrict__ epack,
                           const float* __restrict__ dpk, const float* __restrict__ bvec,
                           const int* __restrict__ batch,
                           float* __restrict__ pooled, int N) {
  __shared__ float sh[4][128];
  __shared__ int sg[4];
  int wave = threadIdx.x >> 6;
  int lane = threadIdx.x & 63;
  int i = blockIdx.x * 4 + wave;
  if (threadIdx.x < 4) sg[threadIdx.x] = -1;
  __syncthreads();
  if (i < N) {
    int r0 = rowptr[i], r1 = rowptr[i + 1];
    unsigned short ps = *(const unsigned short*)(tin + (size_t)i * 128 + 2 * lane);
    float dp = dpk[i];
    float2 bv = *(const float2*)(bvec + 2 * lane);
    float a0, a1;
    gather_node(tin, epack, r0, r1 - r0, lane, a0, a1);
    f32x2 sv = fp8x2_to_f(ps);
    float di = fabsf(dp);
    sh[wave][2 * lane]     = di * (a0 + sv.x) + bv.x;
    sh[wave][2 * lane + 1] = di * (a1 + sv.y) + bv.y;
    if (lane == 0) sg[wave] = batch[i];
  }
  __syncthreads();
  if (threadIdx.x < 128) {
    int c = threadIdx.x;
    float acc = 0.f;
    int cur = sg[0];
    #pragma unroll
    for (int w2 = 0; w2 < 4; ++w2) {
      int gw = sg[w2];
      if (gw < 0) break;
      if (gw != cur) {
        atomicAdd(&pooled[cur * 128 + c], acc);
        acc = 0.f;
        cur = gw;
      }
      acc += sh[w2][c];
    }
    atomicAdd(&pooled[cur * 128 + c], acc);
  }
}

// ---------------- standalone MFMA GEMM: t' = dinv * (h @ W), fp8 out ----------------
__global__ void k_gemm(const unsigned short* __restrict__ h,
                       const unsigned short* __restrict__ wphi,
                       const unsigned short* __restrict__ wplo,
                       const float* __restrict__ dpk,
                       unsigned char* __restrict__ tout, int N) {
  int wave = threadIdx.x >> 6;
  int lane = threadIdx.x & 63;
  int r0 = (blockIdx.x * 4 + wave) * 32;
  if (r0 >= N) return;
  int q = lane >> 4;
  int m = lane & 15;
  const bf16x8* bh_base = (const bf16x8*)wphi;
  const bf16x8* bl_base = (const bf16x8*)wplo;

  f32x4 acc[2][8];
  #pragma unroll
  for (int tt = 0; tt < 2; ++tt)
    #pragma unroll
    for (int ct = 0; ct < 8; ++ct)
      acc[tt][ct] = (f32x4){0.f, 0.f, 0.f, 0.f};

  for (int c = 0; c < 4; ++c) {
    bf16x8 a0 = *(const bf16x8*)(h + (size_t)(r0 + m) * 128 + c * 32 + q * 8);
    bf16x8 a1 = *(const bf16x8*)(h + (size_t)(r0 + 16 + m) * 128 + c * 32 + q * 8);
    #pragma unroll
    for (int ct = 0; ct < 8; ++ct) {
      bf16x8 bh = bh_base[(ct * 4 + c) * 64 + lane];
      bf16x8 bl = bl_base[(ct * 4 + c) * 64 + lane];
      acc[0][ct] = __builtin_amdgcn_mfma_f32_16x16x32_bf16(a0, bh, acc[0][ct], 0, 0, 0);
      acc[0][ct] = __builtin_amdgcn_mfma_f32_16x16x32_bf16(a0, bl, acc[0][ct], 0, 0, 0);
      acc[1][ct] = __builtin_amdgcn_mfma_f32_16x16x32_bf16(a1, bh, acc[1][ct], 0, 0, 0);
      acc[1][ct] = __builtin_amdgcn_mfma_f32_16x16x32_bf16(a1, bl, acc[1][ct], 0, 0, 0);
    }
  }

  #pragma unroll
  for (int tt = 0; tt < 2; ++tt)
    #pragma unroll
    for (int ct = 0; ct < 8; ++ct)
      #pragma unroll
      for (int r = 0; r < 4; ++r) {
        int row = r0 + tt * 16 + q * 4 + r;
        if (row < N) {
          float sc = fabsf(dpk[row]);
          tout[(size_t)row * 128 + ct * 16 + m] = f_to_fp8(sc * acc[tt][ct][r]);
        }
      }
}

// ---------------- fused layer0 (rank-2) + gemm1 -> t1' ----------------
__device__ inline void gemm_tile8(const unsigned short* hT,
                                  const unsigned short* __restrict__ wphi,
                                  const unsigned short* __restrict__ wplo,
                                  const float* __restrict__ dpk,
                                  unsigned char* __restrict__ tout, int i0, int N) {
  int ct = threadIdx.x >> 6;
  int lane = threadIdx.x & 63;
  int q = lane >> 4;
  int m = lane & 15;
  const bf16x8* bh_base = (const bf16x8*)wphi;
  const bf16x8* bl_base = (const bf16x8*)wplo;

  f32x4 acc0 = (f32x4){0.f, 0.f, 0.f, 0.f};
  f32x4 acc1 = (f32x4){0.f, 0.f, 0.f, 0.f};

  #pragma unroll
  for (int c = 0; c < 4; ++c) {
    bf16x8 a0 = *(const bf16x8*)(hT + (m) * 136 + c * 32 + q * 8);
    bf16x8 a1 = *(const bf16x8*)(hT + (16 + m) * 136 + c * 32 + q * 8);
    bf16x8 bh = bh_base[(ct * 4 + c) * 64 + lane];
    bf16x8 bl = bl_base[(ct * 4 + c) * 64 + lane];
    acc0 = __builtin_amdgcn_mfma_f32_16x16x32_bf16(a0, bh, acc0, 0, 0, 0);
    acc0 = __builtin_amdgcn_mfma_f32_16x16x32_bf16(a0, bl, acc0, 0, 0, 0);
    acc1 = __builtin_amdgcn_mfma_f32_16x16x32_bf16(a1, bh, acc1, 0, 0, 0);
    acc1 = __builtin_amdgcn_mfma_f32_16x16x32_bf16(a1, bl, acc1, 0, 0, 0);
  }

  #pragma unroll
  for (int r = 0; r < 4; ++r) {
    int row0 = i0 + q * 4 + r;
    int row1 = row0 + 16;
    if (row0 < N) {
      float sc = fabsf(dpk[row0]);
      tout[(size_t)row0 * 128 + ct * 16 + m] = f_to_fp8(sc * acc0[r]);
    }
    if (row1 < N) {
      float sc = fabsf(dpk[row1]);
      tout[(size_t)row1 * 128 + ct * 16 + m] = f_to_fp8(sc * acc1[r]);
    }
  }
}

__global__ __launch_bounds__(512)
void k_l1_gemm(const int* __restrict__ rowptr,
               const int2* __restrict__ epack,
               const float* __restrict__ dpk, const float* __restrict__ T,
               const float* __restrict__ b0,
               const unsigned short* __restrict__ wphi,
               const unsigned short* __restrict__ wplo,
               unsigned char* __restrict__ tout, int N) {
  __shared__ unsigned short hT[32 * 136];
  int wave = threadIdx.x >> 6;
  int lane = threadIdx.x & 63;
  int i0 = blockIdx.x * 32;

  for (int j = wave * 4; j < wave * 4 + 4; ++j) {
    int i = i0 + j;
    if (i >= N) break;
    int r0 = rowptr[i], r1 = rowptr[i + 1];
    float sabs = 0.f, sneg = 0.f;
    for (int e = r0 + lane; e < r1; e += 64) {
      float wv = __int_as_float(epack[e].y);   // dpk[src]
      float aw = fabsf(wv);
      sabs += aw;
      if (wv < 0.f) sneg += aw;
    }
    for (int mm = 32; mm >= 1; mm >>= 1) {
      sabs += __shfl_xor(sabs, mm, 64);
      sneg += __shfl_xor(sneg, mm, 64);
    }
    float dp = dpk[i];
    float di = fabsf(dp);
    float sn = di * di;
    float c1 = di * sneg;
    float c0 = di * (sabs - sneg);
    if (dp < 0.f) c1 += sn; else c0 += sn;
    float v0 = fmaxf(c0 * T[2 * lane]     + c1 * T[128 + 2 * lane]     + b0[2 * lane],     0.f);
    float v1 = fmaxf(c0 * T[2 * lane + 1] + c1 * T[128 + 2 * lane + 1] + b0[2 * lane + 1], 0.f);
    *(unsigned*)&hT[j * 136 + 2 * lane] = (unsigned)bf16_rtn(v0) | ((unsigned)bf16_rtn(v1) << 16);
  }
  __syncthreads();
  gemm_tile8(hT, wphi, wplo, dpk, tout, i0, N);
}

// ---------------- output head ----------------
__global__ void k_out(const float* __restrict__ pooled, const int* __restrict__ gstart,
                      const int* __restrict__ gend, const float* __restrict__ W_out,
                      const float* __restrict__ b_out, float* __restrict__ out, int G) {
  __shared__ float sp[128];
  int g = blockIdx.x;
  int j = threadIdx.x;
  float cnt = (float)(gend[g] - gstart[g]);
  sp[j] = pooled[g * 128 + j] / fmaxf(cnt, 1.f);
  __syncthreads();
  if (j < 2) {
    float o = b_out[j];
    for (int k = 0; k < 128; ++k)
      o += sp[k] * W_out[k * 2 + j];
    out[g * 2 + j] = o;
  }
}

extern "C" void kernel_launch(void* const* d_in, const int* in_sizes, int n_in,
                              void* d_out, int out_size, void* d_ws, size_t ws_size,
                              hipStream_t stream) {
  const int*   x     = (const int*)d_in[0];
  const int*   ei    = (const int*)d_in[1];
  const int*   batch = (const int*)d_in[2];
  const float* embed = (const float*)d_in[3];
  const float* Ws    = (const float*)d_in[4];
  const float* bs    = (const float*)d_in[5];
  const float* W_out = (const float*)d_in[6];
  const float* b_out = (const float*)d_in[7];
  float* out = (float*)d_out;

  int N = in_sizes[2];
  int E = in_sizes[1] / 2;
  int G = out_size / 2;

  const int* src = ei;
  const int* dst = ei + E;

  char* w = (char*)d_ws;
  auto alloc = [&](size_t bytes) {
    char* p = w;
    w += (bytes + 255) & ~(size_t)255;
    return p;
  };
  int*   deg    = (int*)  alloc((size_t)N * 4);
  float* dpk    = (float*)alloc((size_t)N * 4);
  int*   rowptr = (int*)  alloc((size_t)(N + 1) * 4);
  int*   posr   = (int*)  alloc((size_t)E * 4);
  int*   bsum   = (int*)  alloc(512 * 4);
  int*   boff   = (int*)  alloc(512 * 4);
  // gstart/gend/pooled contiguous -> zeroed together in k_init
  int*   gstart = (int*)  alloc((size_t)G * 4);
  int*   gend   = (int*)  alloc((size_t)G * 4);
  float* pooled = (float*)alloc((size_t)G * 128 * 4);
  float* T      = (float*)alloc(256 * 4);
  unsigned short* wphi = (unsigned short*)alloc((size_t)3 * 16384 * 2);
  unsigned short* wplo = (unsigned short*)alloc((size_t)3 * 16384 * 2);
  int2*  epack  = (int2*) alloc((size_t)E * 8);
  unsigned short* h = (unsigned short*)alloc((size_t)N * 128 * 2);
  unsigned char* t_a = (unsigned char*)alloc((size_t)N * 128);
  unsigned char* t_b = (unsigned char*)alloc((size_t)N * 128);

  int nbN = (N + 255) / 256;
  int nbE = (E + 255) / 256;
  int ntile = (N + 31) / 32;
  int nwb = (N + 3) / 4;            // 1 wave/node, 256-thr blocks
  int ngemm = (N + 127) / 128;      // 4 waves x 32 rows
  int M = G * 130;                  // gstart + gend + pooled (4B elems, contiguous)

  k_init<<<nbN, 256, 0, stream>>>(deg, gstart, N, M, Ws, embed, wphi, wplo, T);
  k_hist<<<nbE, 256, 0, stream>>>(dst, deg, posr, E);
  k_scan1<<<nbN, 256, 0, stream>>>(deg, rowptr, bsum, dpk, x, batch, gstart, gend, N);
  k_scan2<<<1, 512, 0, stream>>>(bsum, boff, nbN);
  k_scan3<<<nbN, 256, 0, stream>>>(rowptr, boff, N, E);
  k_scatter<<<nbE, 256, 0, stream>>>(src, dst, posr, rowptr, dpk, epack, E);

  // layer0 (rank-2) + gemm1 -> t_a (= dinv * h1@W1)
  k_l1_gemm<<<ntile, 512, 0, stream>>>(rowptr, epack, dpk, T, bs,
                                       wphi, wplo, t_a, N);
  // layer1: h = relu(dinv*(sum t_a' + self) + b1); t_b = dinv * h@W2
  k_agg<<<nwb, 256, 0, stream>>>(t_a, rowptr, epack, dpk, bs + 128, h, N);
  k_gemm<<<ngemm, 256, 0, stream>>>(h, wphi + 16384, wplo + 16384, dpk, t_b, N);
  // layer2
  k_agg<<<nwb, 256, 0, stream>>>(t_b, rowptr, epack, dpk, bs + 256, h, N);
  k_gemm<<<ngemm, 256, 0, stream>>>(h, wphi + 32768, wplo + 32768, dpk, t_a, N);
  // layer3 (no relu) fused with mean-pool
  k_agg_pool<<<nwb, 256, 0, stream>>>(t_a, rowptr, epack, dpk, bs + 384,
                                      batch, pooled, N);
  k_out<<<G, 128, 0, stream>>>(pooled, gstart, gend, W_out, b_out, out, G);
}

// Round 16
// 334.029 us; speedup vs baseline: 1.1845x; 1.1845x over previous
//
#include <hip/hip_runtime.h>

typedef __attribute__((ext_vector_type(8))) short bf16x8;
typedef __attribute__((ext_vector_type(4))) float f32x4;
typedef __attribute__((ext_vector_type(2))) float f32x2;

// bf16 round-to-nearest-even
__device__ inline unsigned short bf16_rtn(float f) {
  unsigned u = __float_as_uint(f);
  unsigned r = u + 0x7fffu + ((u >> 16) & 1u);
  return (unsigned short)(r >> 16);
}

// split fp32 into hi/lo bf16 (for W only)
__device__ inline void split_bf16(float f, unsigned short& hi, unsigned short& lo) {
  hi = bf16_rtn(f);
  float fh = __uint_as_float((unsigned)hi << 16);
  lo = bf16_rtn(f - fh);
}

__device__ inline float bf16_to_f(unsigned short v) {
  return __uint_as_float((unsigned)v << 16);
}

// fp8 e4m3 (OCP) pack/unpack via HW converters
__device__ inline unsigned char f_to_fp8(float f) {
  int r = __builtin_amdgcn_cvt_pk_fp8_f32(f, f, 0, false);
  return (unsigned char)(r & 0xff);
}
__device__ inline f32x2 fp8x2_to_f(unsigned short v) {
  return __builtin_amdgcn_cvt_pk_f32_fp8((int)v, false);
}

// ---------------- init: zero deg + gstart/gend/pooled, prep W hi/lo, T ----------------
__global__ void k_init(int* __restrict__ deg, int* __restrict__ gpz, int N, int M,
                       const float* __restrict__ Ws, const float* __restrict__ embed,
                       unsigned short* __restrict__ wphi,
                       unsigned short* __restrict__ wplo,
                       float* __restrict__ T) {
  int i = blockIdx.x * 256 + threadIdx.x;
  if (i < N) deg[i] = 0;
  if (i < M) gpz[i] = 0;
  int l = blockIdx.x;
  if (l < 3) {
    const float* W = Ws + (size_t)(l + 1) * 128 * 128;
    unsigned short* dh = wphi + (size_t)l * 16384;
    unsigned short* dl = wplo + (size_t)l * 16384;
    for (int idx = threadIdx.x; idx < 16384; idx += 256) {
      int j = idx & 7;
      int lane = (idx >> 3) & 63;
      int c = (idx >> 9) & 3;
      int ct = idx >> 11;
      int k = c * 32 + ((lane >> 4) * 8) + j;
      int n = ct * 16 + (lane & 15);
      unsigned short hi, lo;
      split_bf16(W[k * 128 + n], hi, lo);
      dh[idx] = hi;
      dl[idx] = lo;
    }
  } else if (l == 3) {
    int t = threadIdx.x;
    int r = t >> 7, c = t & 127;
    float acc = 0.f;
    for (int k = 0; k < 128; ++k)
      acc += embed[r * 128 + k] * Ws[k * 128 + c];
    T[r * 128 + c] = acc;
  }
}

// ---------------- CSR construction ----------------

__global__ void k_hist(const int* __restrict__ dst, int* __restrict__ deg,
                       int* __restrict__ posr, int E) {
  int e = blockIdx.x * 256 + threadIdx.x;
  if (e < E) posr[e] = atomicAdd(&deg[dst[e]], 1);
}

__global__ void k_scan1(const int* __restrict__ deg, int* __restrict__ rowptr,
                        int* __restrict__ bsum, float* __restrict__ dpk,
                        const int* __restrict__ x, const int* __restrict__ batch,
                        int* __restrict__ gstart, int* __restrict__ gend, int N) {
  __shared__ int s[256];
  int t = threadIdx.x;
  int i = blockIdx.x * 256 + t;
  int v = (i < N) ? deg[i] : 0;
  if (i < N) {
    float di = rsqrtf((float)v + 1.0f);
    dpk[i] = x[i] ? -di : di;
    int g = batch[i];
    if (i == 0 || batch[i - 1] != g) gstart[g] = i;
    if (i == N - 1 || batch[i + 1] != g) gend[g] = i + 1;
  }
  s[t] = v;
  __syncthreads();
  for (int off = 1; off < 256; off <<= 1) {
    int u = (t >= off) ? s[t - off] : 0;
    __syncthreads();
    s[t] += u;
    __syncthreads();
  }
  if (i < N) rowptr[i] = s[t] - v;
  if (t == 255) bsum[blockIdx.x] = s[255];
}

__global__ void k_scan2(const int* __restrict__ bsum, int* __restrict__ boff, int nb) {
  __shared__ int s[512];
  int t = threadIdx.x;
  int v = (t < nb) ? bsum[t] : 0;
  s[t] = v;
  __syncthreads();
  for (int off = 1; off < 512; off <<= 1) {
    int u = (t >= off) ? s[t - off] : 0;
    __syncthreads();
    s[t] += u;
    __syncthreads();
  }
  boff[t] = s[t] - v;
}

__global__ void k_scan3(int* __restrict__ rowptr, const int* __restrict__ boff,
                        int N, int E) {
  int i = blockIdx.x * 256 + threadIdx.x;
  if (i < N) rowptr[i] += boff[i >> 8];
  if (i == 0) rowptr[N] = E;
}

__global__ void k_scatter(const int* __restrict__ src, const int* __restrict__ dst,
                          const int* __restrict__ posr, const int* __restrict__ rowptr,
                          const float* __restrict__ dpk,
                          int2* __restrict__ epack, int E) {
  int e = blockIdx.x * 256 + threadIdx.x;
  if (e >= E) return;
  int s = src[e], d = dst[e];
  int pos = rowptr[d] + posr[e];
  epack[pos] = make_int2(s, __float_as_int(dpk[s]));
}

// ---------------- per-node gather (fp8 t' rows, weightless), unroll-4 ----------------
// Straight-line unrolled loads (NO per-load predication): the compiler keeps
// 4 loads outstanding under one s_waitcnt. r14's predicated batch-8 regressed
// 59.7->77.6 us (guards force per-load waits) — do not reintroduce.
__device__ inline void gather_node(const unsigned char* __restrict__ tin,
                                   const int2* __restrict__ epack,
                                   int r0, int deg, int lane,
                                   float& a0, float& a1) {
  int dcap = deg < 64 ? deg : 64;
  int sl = 0;
  if (lane < dcap) sl = epack[r0 + lane].x;
  a0 = 0.f; a1 = 0.f;
  int e = 0;
  for (; e + 4 <= dcap; e += 4) {
    int s0 = __shfl(sl, e, 64),     s1 = __shfl(sl, e + 1, 64);
    int s2 = __shfl(sl, e + 2, 64), s3 = __shfl(sl, e + 3, 64);
    unsigned short p0 = *(const unsigned short*)(tin + (size_t)s0 * 128 + 2 * lane);
    unsigned short p1 = *(const unsigned short*)(tin + (size_t)s1 * 128 + 2 * lane);
    unsigned short p2 = *(const unsigned short*)(tin + (size_t)s2 * 128 + 2 * lane);
    unsigned short p3 = *(const unsigned short*)(tin + (size_t)s3 * 128 + 2 * lane);
    f32x2 v0 = fp8x2_to_f(p0), v1 = fp8x2_to_f(p1);
    f32x2 v2 = fp8x2_to_f(p2), v3 = fp8x2_to_f(p3);
    a0 += v0.x + v1.x + v2.x + v3.x;
    a1 += v0.y + v1.y + v2.y + v3.y;
  }
  for (; e < dcap; ++e) {
    int s = __shfl(sl, e, 64);
    unsigned short p = *(const unsigned short*)(tin + (size_t)s * 128 + 2 * lane);
    f32x2 v = fp8x2_to_f(p);
    a0 += v.x;
    a1 += v.y;
  }
  for (int ee = r0 + 64; ee < r0 + deg; ++ee) {   // rare: deg > 64
    int s = epack[ee].x;
    unsigned short p = *(const unsigned short*)(tin + (size_t)s * 128 + 2 * lane);
    f32x2 v = fp8x2_to_f(p);
    a0 += v.x;
    a1 += v.y;
  }
}

// ---------------- standalone aggregate: h = relu(dinv_i*(sum t' + t'_i) + b) ----------------
__global__ void k_agg(const unsigned char* __restrict__ tin,
                      const int* __restrict__ rowptr,
                      const int2* __restrict__ epack,
                      const float* __restrict__ dpk, const float* __restrict__ bvec,
                      unsigned short* __restrict__ h, int N) {
  int i = (blockIdx.x * blockDim.x + threadIdx.x) >> 6;
  int lane = threadIdx.x & 63;
  if (i >= N) return;
  int r0 = rowptr[i], r1 = rowptr[i + 1];
  // prefetch independents before the gather (unguarded loads)
  unsigned short ps = *(const unsigned short*)(tin + (size_t)i * 128 + 2 * lane);
  float dp = dpk[i];
  float2 bv = *(const float2*)(bvec + 2 * lane);
  float a0, a1;
  gather_node(tin, epack, r0, r1 - r0, lane, a0, a1);
  f32x2 sv = fp8x2_to_f(ps);
  float di = fabsf(dp);
  a0 = fmaxf(di * (a0 + sv.x) + bv.x, 0.f);
  a1 = fmaxf(di * (a1 + sv.y) + bv.y, 0.f);
  *(unsigned*)(h + (size_t)i * 128 + 2 * lane) =
      (unsigned)bf16_rtn(a0) | ((unsigned)bf16_rtn(a1) << 16);
}

// ---------------- fused final aggregate + mean-pool (block = 4 nodes) ----------------
__global__ void k_agg_pool(const unsigned char* __restrict__ tin,
                           const int* __restrict__ rowptr,
                           const int2* __restrict__ epack,
                           const float* __restrict__ dpk, const float* __restrict__ bvec,
                           const int* __restrict__ batch,
                           float* __restrict__ pooled, int N) {
  __shared__ float sh[4][128];
  __shared__ int sg[4];
  int wave = threadIdx.x >> 6;
  int lane = threadIdx.x & 63;
  int i = blockIdx.x * 4 + wave;
  if (threadIdx.x < 4) sg[threadIdx.x] = -1;
  __syncthreads();
  if (i < N) {
    int r0 = rowptr[i], r1 = rowptr[i + 1];
    unsigned short ps = *(const unsigned short*)(tin + (size_t)i * 128 + 2 * lane);
    float dp = dpk[i];
    float2 bv = *(const float2*)(bvec + 2 * lane);
    float a0, a1;
    gather_node(tin, epack, r0, r1 - r0, lane, a0, a1);
    f32x2 sv = fp8x2_to_f(ps);
    float di = fabsf(dp);
    sh[wave][2 * lane]     = di * (a0 + sv.x) + bv.x;
    sh[wave][2 * lane + 1] = di * (a1 + sv.y) + bv.y;
    if (lane == 0) sg[wave] = batch[i];
  }
  __syncthreads();
  if (threadIdx.x < 128) {
    int c = threadIdx.x;
    float acc = 0.f;
    int cur = sg[0];
    #pragma unroll
    for (int w2 = 0; w2 < 4; ++w2) {
      int gw = sg[w2];
      if (gw < 0) break;
      if (gw != cur) {
        atomicAdd(&pooled[cur * 128 + c], acc);
        acc = 0.f;
        cur = gw;
      }
      acc += sh[w2][c];
    }
    atomicAdd(&pooled[cur * 128 + c], acc);
  }
}

// ---------------- standalone MFMA GEMM: t' = dinv * (h @ W), fp8 out ----------------
__global__ void k_gemm(const unsigned short* __restrict__ h,
                       const unsigned short* __restrict__ wphi,
                       const unsigned short* __restrict__ wplo,
                       const float* __restrict__ dpk,
                       unsigned char* __restrict__ tout, int N) {
  int wave = threadIdx.x >> 6;
  int lane = threadIdx.x & 63;
  int r0 = (blockIdx.x * 4 + wave) * 32;
  if (r0 >= N) return;
  int q = lane >> 4;
  int m = lane & 15;
  const bf16x8* bh_base = (const bf16x8*)wphi;
  const bf16x8* bl_base = (const bf16x8*)wplo;

  f32x4 acc[2][8];
  #pragma unroll
  for (int tt = 0; tt < 2; ++tt)
    #pragma unroll
    for (int ct = 0; ct < 8; ++ct)
      acc[tt][ct] = (f32x4){0.f, 0.f, 0.f, 0.f};

  for (int c = 0; c < 4; ++c) {
    bf16x8 a0 = *(const bf16x8*)(h + (size_t)(r0 + m) * 128 + c * 32 + q * 8);
    bf16x8 a1 = *(const bf16x8*)(h + (size_t)(r0 + 16 + m) * 128 + c * 32 + q * 8);
    #pragma unroll
    for (int ct = 0; ct < 8; ++ct) {
      bf16x8 bh = bh_base[(ct * 4 + c) * 64 + lane];
      bf16x8 bl = bl_base[(ct * 4 + c) * 64 + lane];
      acc[0][ct] = __builtin_amdgcn_mfma_f32_16x16x32_bf16(a0, bh, acc[0][ct], 0, 0, 0);
      acc[0][ct] = __builtin_amdgcn_mfma_f32_16x16x32_bf16(a0, bl, acc[0][ct], 0, 0, 0);
      acc[1][ct] = __builtin_amdgcn_mfma_f32_16x16x32_bf16(a1, bh, acc[1][ct], 0, 0, 0);
      acc[1][ct] = __builtin_amdgcn_mfma_f32_16x16x32_bf16(a1, bl, acc[1][ct], 0, 0, 0);
    }
  }

  #pragma unroll
  for (int tt = 0; tt < 2; ++tt)
    #pragma unroll
    for (int ct = 0; ct < 8; ++ct)
      #pragma unroll
      for (int r = 0; r < 4; ++r) {
        int row = r0 + tt * 16 + q * 4 + r;
        if (row < N) {
          float sc = fabsf(dpk[row]);
          tout[(size_t)row * 128 + ct * 16 + m] = f_to_fp8(sc * acc[tt][ct][r]);
        }
      }
}

// ---------------- fused layer0 (rank-2) + gemm1 -> t1' ----------------
__device__ inline void gemm_tile8(const unsigned short* hT,
                                  const unsigned short* __restrict__ wphi,
                                  const unsigned short* __restrict__ wplo,
                                  const float* __restrict__ dpk,
                                  unsigned char* __restrict__ tout, int i0, int N) {
  int ct = threadIdx.x >> 6;
  int lane = threadIdx.x & 63;
  int q = lane >> 4;
  int m = lane & 15;
  const bf16x8* bh_base = (const bf16x8*)wphi;
  const bf16x8* bl_base = (const bf16x8*)wplo;

  f32x4 acc0 = (f32x4){0.f, 0.f, 0.f, 0.f};
  f32x4 acc1 = (f32x4){0.f, 0.f, 0.f, 0.f};

  #pragma unroll
  for (int c = 0; c < 4; ++c) {
    bf16x8 a0 = *(const bf16x8*)(hT + (m) * 136 + c * 32 + q * 8);
    bf16x8 a1 = *(const bf16x8*)(hT + (16 + m) * 136 + c * 32 + q * 8);
    bf16x8 bh = bh_base[(ct * 4 + c) * 64 + lane];
    bf16x8 bl = bl_base[(ct * 4 + c) * 64 + lane];
    acc0 = __builtin_amdgcn_mfma_f32_16x16x32_bf16(a0, bh, acc0, 0, 0, 0);
    acc0 = __builtin_amdgcn_mfma_f32_16x16x32_bf16(a0, bl, acc0, 0, 0, 0);
    acc1 = __builtin_amdgcn_mfma_f32_16x16x32_bf16(a1, bh, acc1, 0, 0, 0);
    acc1 = __builtin_amdgcn_mfma_f32_16x16x32_bf16(a1, bl, acc1, 0, 0, 0);
  }

  #pragma unroll
  for (int r = 0; r < 4; ++r) {
    int row0 = i0 + q * 4 + r;
    int row1 = row0 + 16;
    if (row0 < N) {
      float sc = fabsf(dpk[row0]);
      tout[(size_t)row0 * 128 + ct * 16 + m] = f_to_fp8(sc * acc0[r]);
    }
    if (row1 < N) {
      float sc = fabsf(dpk[row1]);
      tout[(size_t)row1 * 128 + ct * 16 + m] = f_to_fp8(sc * acc1[r]);
    }
  }
}

__global__ __launch_bounds__(512)
void k_l1_gemm(const int* __restrict__ rowptr,
               const int2* __restrict__ epack,
               const float* __restrict__ dpk, const float* __restrict__ T,
               const float* __restrict__ b0,
               const unsigned short* __restrict__ wphi,
               const unsigned short* __restrict__ wplo,
               unsigned char* __restrict__ tout, int N) {
  __shared__ unsigned short hT[32 * 136];
  int wave = threadIdx.x >> 6;
  int lane = threadIdx.x & 63;
  int i0 = blockIdx.x * 32;

  for (int j = wave * 4; j < wave * 4 + 4; ++j) {
    int i = i0 + j;
    if (i >= N) break;
    int r0 = rowptr[i], r1 = rowptr[i + 1];
    float sabs = 0.f, sneg = 0.f;
    for (int e = r0 + lane; e < r1; e += 64) {
      float wv = __int_as_float(epack[e].y);   // dpk[src]
      float aw = fabsf(wv);
      sabs += aw;
      if (wv < 0.f) sneg += aw;
    }
    for (int mm = 32; mm >= 1; mm >>= 1) {
      sabs += __shfl_xor(sabs, mm, 64);
      sneg += __shfl_xor(sneg, mm, 64);
    }
    float dp = dpk[i];
    float di = fabsf(dp);
    float sn = di * di;
    float c1 = di * sneg;
    float c0 = di * (sabs - sneg);
    if (dp < 0.f) c1 += sn; else c0 += sn;
    float v0 = fmaxf(c0 * T[2 * lane]     + c1 * T[128 + 2 * lane]     + b0[2 * lane],     0.f);
    float v1 = fmaxf(c0 * T[2 * lane + 1] + c1 * T[128 + 2 * lane + 1] + b0[2 * lane + 1], 0.f);
    *(unsigned*)&hT[j * 136 + 2 * lane] = (unsigned)bf16_rtn(v0) | ((unsigned)bf16_rtn(v1) << 16);
  }
  __syncthreads();
  gemm_tile8(hT, wphi, wplo, dpk, tout, i0, N);
}

// ---------------- output head ----------------
__global__ void k_out(const float* __restrict__ pooled, const int* __restrict__ gstart,
                      const int* __restrict__ gend, const float* __restrict__ W_out,
                      const float* __restrict__ b_out, float* __restrict__ out, int G) {
  __shared__ float sp[128];
  int g = blockIdx.x;
  int j = threadIdx.x;
  float cnt = (float)(gend[g] - gstart[g]);
  sp[j] = pooled[g * 128 + j] / fmaxf(cnt, 1.f);
  __syncthreads();
  if (j < 2) {
    float o = b_out[j];
    for (int k = 0; k < 128; ++k)
      o += sp[k] * W_out[k * 2 + j];
    out[g * 2 + j] = o;
  }
}

extern "C" void kernel_launch(void* const* d_in, const int* in_sizes, int n_in,
                              void* d_out, int out_size, void* d_ws, size_t ws_size,
                              hipStream_t stream) {
  const int*   x     = (const int*)d_in[0];
  const int*   ei    = (const int*)d_in[1];
  const int*   batch = (const int*)d_in[2];
  const float* embed = (const float*)d_in[3];
  const float* Ws    = (const float*)d_in[4];
  const float* bs    = (const float*)d_in[5];
  const float* W_out = (const float*)d_in[6];
  const float* b_out = (const float*)d_in[7];
  float* out = (float*)d_out;

  int N = in_sizes[2];
  int E = in_sizes[1] / 2;
  int G = out_size / 2;

  const int* src = ei;
  const int* dst = ei + E;

  char* w = (char*)d_ws;
  auto alloc = [&](size_t bytes) {
    char* p = w;
    w += (bytes + 255) & ~(size_t)255;
    return p;
  };
  int*   deg    = (int*)  alloc((size_t)N * 4);
  float* dpk    = (float*)alloc((size_t)N * 4);
  int*   rowptr = (int*)  alloc((size_t)(N + 1) * 4);
  int*   posr   = (int*)  alloc((size_t)E * 4);
  int*   bsum   = (int*)  alloc(512 * 4);
  int*   boff   = (int*)  alloc(512 * 4);
  // gstart/gend/pooled contiguous -> zeroed together in k_init
  int*   gstart = (int*)  alloc((size_t)G * 4);
  int*   gend   = (int*)  alloc((size_t)G * 4);
  float* pooled = (float*)alloc((size_t)G * 128 * 4);
  float* T      = (float*)alloc(256 * 4);
  unsigned short* wphi = (unsigned short*)alloc((size_t)3 * 16384 * 2);
  unsigned short* wplo = (unsigned short*)alloc((size_t)3 * 16384 * 2);
  int2*  epack  = (int2*) alloc((size_t)E * 8);
  unsigned short* h = (unsigned short*)alloc((size_t)N * 128 * 2);
  unsigned char* t_a = (unsigned char*)alloc((size_t)N * 128);
  unsigned char* t_b = (unsigned char*)alloc((size_t)N * 128);

  int nbN = (N + 255) / 256;
  int nbE = (E + 255) / 256;
  int ntile = (N + 31) / 32;
  int nwb = (N + 3) / 4;            // 1 wave/node, 256-thr blocks
  int ngemm = (N + 127) / 128;      // 4 waves x 32 rows
  int M = G * 130;                  // gstart + gend + pooled (4B elems, contiguous)

  k_init<<<nbN, 256, 0, stream>>>(deg, gstart, N, M, Ws, embed, wphi, wplo, T);
  k_hist<<<nbE, 256, 0, stream>>>(dst, deg, posr, E);
  k_scan1<<<nbN, 256, 0, stream>>>(deg, rowptr, bsum, dpk, x, batch, gstart, gend, N);
  k_scan2<<<1, 512, 0, stream>>>(bsum, boff, nbN);
  k_scan3<<<nbN, 256, 0, stream>>>(rowptr, boff, N, E);
  k_scatter<<<nbE, 256, 0, stream>>>(src, dst, posr, rowptr, dpk, epack, E);

  // layer0 (rank-2) + gemm1 -> t_a (= dinv * h1@W1)
  k_l1_gemm<<<ntile, 512, 0, stream>>>(rowptr, epack, dpk, T, bs,
                                       wphi, wplo, t_a, N);
  // layer1: h = relu(dinv*(sum t_a' + self) + b1); t_b = dinv * h@W2
  k_agg<<<nwb, 256, 0, stream>>>(t_a, rowptr, epack, dpk, bs + 128, h, N);
  k_gemm<<<ngemm, 256, 0, stream>>>(h, wphi + 16384, wplo + 16384, dpk, t_b, N);
  // layer2
  k_agg<<<nwb, 256, 0, stream>>>(t_b, rowptr, epack, dpk, bs + 256, h, N);
  k_gemm<<<ngemm, 256, 0, stream>>>(h, wphi + 32768, wplo + 32768, dpk, t_a, N);
  // layer3 (no relu) fused with mean-pool
  k_agg_pool<<<nwb, 256, 0, stream>>>(t_a, rowptr, epack, dpk, bs + 384,
                                      batch, pooled, N);
  k_out<<<G, 128, 0, stream>>>(pooled, gstart, gend, W_out, b_out, out, G);
}